// Round 11
// baseline (303.623 us; speedup 1.0000x reference)
//
#include <hip/hip_runtime.h>
#include <cstdint>

typedef unsigned int u32;
typedef unsigned short u16;
typedef _Float16 h2 __attribute__((ext_vector_type(2)));
typedef _Float16 v8h __attribute__((ext_vector_type(8)));
typedef float f32x4 __attribute__((ext_vector_type(4)));

// ---------------- workspace byte offsets (written by vit_prep) ----------------
#define WS_W1A   0        // [3*16*49][8] f16 : W1 i<8   (Q rows pre-scaled 1/7)
#define WS_W1B   37632    // [3*16*49][8] f16 : W1 i 8..16
#define WS_CQ    75264    // f32[2352]  pos-emb-folded bias (Q part pre-scaled)
#define WS_W2A   84672    // [3*8*49][8] f16 : W2 i<8 (Q rows pre-scaled 1/7)
#define WS_W2B   103488   // [3*8*49][8] f16 : W2 i 8..16
#define WS_F1H   122304   // u32[16*196] fc1 weights as f16 pairs (bias NOT folded)
#define WS_F1B   134848   // f32[16]
#define WS_F2W   134912   // f32[160]
#define WS_F2B   135552   // f32[10]

__device__ __forceinline__ u32 packh2(float a, float b) {
  h2 h; h.x = (_Float16)a; h.y = (_Float16)b;
  return __builtin_bit_cast(u32, h);
}
__device__ __forceinline__ float dot2u(u32 a, u32 b, float c) {
#if __has_builtin(__builtin_amdgcn_fdot2)
  return __builtin_amdgcn_fdot2(__builtin_bit_cast(h2, a), __builtin_bit_cast(h2, b), c, false);
#else
  h2 ha = __builtin_bit_cast(h2, a), hb = __builtin_bit_cast(h2, b);
  return c + (float)ha.x * (float)hb.x + (float)ha.y * (float)hb.y;
#endif
}
__device__ __forceinline__ float dot16(const u32* t, uint4 a, uint4 b, float c) {
  c = dot2u(t[0], a.x, c); c = dot2u(t[1], a.y, c);
  c = dot2u(t[2], a.z, c); c = dot2u(t[3], a.w, c);
  c = dot2u(t[4], b.x, c); c = dot2u(t[5], b.y, c);
  c = dot2u(t[6], b.z, c); c = dot2u(t[7], b.w, c);
  return c;
}

// Nontemporal float4 load for x (streamed once; keeps L2 for the weight set).
__device__ __forceinline__ f32x4 ldnt(const float* p) {
  return __builtin_nontemporal_load((const f32x4*)p);
}

// Wave-level LDS fence (for the wave-private tail phases).
__device__ __forceinline__ void wfence() {
  __builtin_amdgcn_sched_barrier(0);
  asm volatile("s_waitcnt lgkmcnt(0)" ::: "memory");
  __builtin_amdgcn_sched_barrier(0);
}

// ---------------- prep (weights only, 27 blocks) ----------------
extern "C" __global__ void vit_prep(
    const float* __restrict__ pe,
    const float* __restrict__ wq1, const float* __restrict__ wk1, const float* __restrict__ wv1,
    const float* __restrict__ wq2, const float* __restrict__ wk2, const float* __restrict__ wv2,
    const float* __restrict__ fw1, const float* __restrict__ fb1,
    const float* __restrict__ fw2, const float* __restrict__ fb2,
    char* __restrict__ ws)
{
  const int t = blockIdx.x * 256 + threadIdx.x;
  _Float16* w1aH = (_Float16*)(ws + WS_W1A);
  _Float16* w1bH = (_Float16*)(ws + WS_W1B);
  float*    cq   = (float*)(ws + WS_CQ);
  _Float16* w2aH = (_Float16*)(ws + WS_W2A);
  _Float16* w2bH = (_Float16*)(ws + WS_W2B);
  u32* f1h = (u32*)(ws + WS_F1H);
  float* o1b = (float*)(ws + WS_F1B);
  float* o2w = (float*)(ws + WS_F2W);
  float* o2b = (float*)(ws + WS_F2B);

  if (t < 2352) {                       // W1 rows: t = (p*16+o)*49+s
    int p = t / 784, rem = t % 784;
    int o = rem / 49, s = rem % 49;
    const float* W = (p == 0 ? wq1 : (p == 1 ? wk1 : wv1)) + s*512 + o*32;
    float sc = (p == 0) ? (1.0f/7.0f) : 1.0f;   // fold attn scale into Q
    #pragma unroll
    for (int i = 0; i < 8; ++i) w1aH[t*8 + i] = (_Float16)(W[i] * sc);
    #pragma unroll
    for (int i = 0; i < 8; ++i) w1bH[t*8 + i] = (_Float16)(W[8 + i] * sc);
    float acc = 0.f;
    #pragma unroll
    for (int i = 0; i < 16; ++i) acc += pe[s*16 + i] * W[16 + i];
    cq[t] = acc * sc;
  } else if (t < 3528) {                // W2 rows: u = (p*8+o)*49+s
    int u = t - 2352;
    int p = u / 392, rem = u % 392;
    int o = rem / 49, s = rem % 49;
    const float* W = (p == 0 ? wq2 : (p == 1 ? wk2 : wv2)) + s*128 + o*16;
    float sc = (p == 0) ? (1.0f/7.0f) : 1.0f;
    #pragma unroll
    for (int i = 0; i < 8; ++i) w2aH[u*8 + i] = (_Float16)(W[i] * sc);
    #pragma unroll
    for (int i = 0; i < 8; ++i) w2bH[u*8 + i] = (_Float16)(W[8 + i] * sc);
  } else if (t < 6664) {                // fc1 f16 pairs: u = h*196 + jc
    int u = t - 3528;
    int h = u / 196, jc = u % 196;
    f1h[u] = packh2(fw1[h*392 + 2*jc], fw1[h*392 + 2*jc + 1]);
  } else if (t < 6680) {
    int u = t - 6664; o1b[u] = fb1[u];
  } else if (t < 6840) {
    int u = t - 6680; o2w[u] = fw2[u];
  } else if (t < 6850) {
    int u = t - 6840; o2b[u] = fb2[u];
  }
}

// ---------------- main fused kernel ----------------
// Block = 256 threads (4 waves), 8 samples/block, grid 2048. NEW: proj1 via
// MFMA. LDS: g f16[8][49][16] @0 (12544 B), then 8 sample regions of 4096 B
// @12544 (identical layout to R8). Phase plan:
//   P1': all 256 threads patchify 392 (b,s) patches into g (nt x loads)
//   __syncthreads
//   P2': per wave, ~12 patches x 3 MFMA (16x16x32_f16, K zero-padded to 32):
//        D(16b x 16o) = tok(16b x 16i) @ W[s]^T + bias(cq).  A from g, B = one
//        16B load of the prepped weight row, C init = cq (pe-folded bias).
//        Q/K written to [o][56] region image; V overwrites g[b][s] in place
//        (dead after this wave's own A-read; same-wave LDS is in-order).
//   __syncthreads; tail (P3..softmax10) = R8 verbatim, except P4a reads
//        v1h from g instead of registers.
// MFMA layouts (m89-verified family): A row=l&15,k=(l>>4)*8+i; B col=l&15,
// k=(l>>4)*8+i; C/D col=l&15,row=(l>>4)*4+j. Rows b>=8 discarded (8 samples).
extern "C" __global__ void __launch_bounds__(256, 2)
vit_main(const float* __restrict__ x, const char* __restrict__ ws, float* __restrict__ out)
{
  __shared__ uint4 smem4[45312 / 16];
  char* smem = (char*)smem4;
  const u32 tid  = threadIdx.x;
  const u32 lane = tid & 63u;
  const u32 wv   = tid >> 6;

  const float* gcq = (const float*)(ws + WS_CQ);
  const uint4* g2a = (const uint4*)(ws + WS_W2A);
  const uint4* g2b = (const uint4*)(ws + WS_W2B);
  const uint4* f1hg = (const uint4*)(ws + WS_F1H);
  const float* f1bg = (const float*)(ws + WS_F1B);
  const float* f2wg = (const float*)(ws + WS_F2W);
  const float* f2bg = (const float*)(ws + WS_F2B);

  char* gbase = smem;                 // g f16[8][49][16]
  char* pw = smem + 12544 + wv * 8192;
  const u32 s = lane;

  const u32 bbase = blockIdx.x * 8u + wv * 2u;

  u32 th4[2][8];   // tok2 pairs
  u32 v2h[2][4];   // V2 e-pairs

  // ---- P1': cooperative patchify -> g (nt x reads) ----
  #pragma unroll
  for (int it = 0; it < 2; ++it) {
    const int p = (int)tid + it*256;
    if (p < 392) {
      const int b = p / 49, ps = p - b*49;
      const int pr = ps / 7, pc = ps - pr*7;
      const float* xb = x + (size_t)(blockIdx.x * 8u + (u32)b) * 2352u;
      u32 og[8];
      #pragma unroll
      for (int r = 0; r < 4; ++r) {
        const float* rp = xb + (4*pr + r) * 28 + 4*pc;
        f32x4 rr = ldnt(rp);
        f32x4 gg = ldnt(rp + 784);
        f32x4 bb = ldnt(rp + 1568);
        float g0 = 0.299f*rr.x + 0.587f*gg.x + 0.114f*bb.x;
        float g1 = 0.299f*rr.y + 0.587f*gg.y + 0.114f*bb.y;
        float g2 = 0.299f*rr.z + 0.587f*gg.z + 0.114f*bb.z;
        float g3 = 0.299f*rr.w + 0.587f*gg.w + 0.114f*bb.w;
        og[r*2]   = packh2(g0, g1);
        og[r*2+1] = packh2(g2, g3);
      }
      uint4* gq = (uint4*)(gbase + b*1568 + ps*32);
      gq[0] = make_uint4(og[0], og[1], og[2], og[3]);
      gq[1] = make_uint4(og[4], og[5], og[6], og[7]);
    }
  }
  __syncthreads();

  // ---- P2': proj1 via MFMA; wave w owns s in [w*13, min(49,w*13+13)) ----
  {
    const int o  = (int)(lane & 15u);     // output col (and A row)
    const int ck = (int)(lane >> 4);      // k-chunk: 0,1 real, 2,3 zero-pad
    const int s0 = (int)wv * 13;
    const int s1 = (s0 + 13 < 49) ? s0 + 13 : 49;
    const char* wrow = ws + WS_W1A + (size_t)ck * 37632;  // w1a (ck=0) / w1b (ck=1)
    #pragma unroll 1
    for (int sp = s0; sp < s1; ++sp) {
      const int r0 = o*49 + sp;
      v8h av = (v8h)0, bq = (v8h)0, bk = (v8h)0, bv = (v8h)0;
      if (ck < 2) {
        av = *(const v8h*)(gbase + ((size_t)(o & 7))*1568 + sp*32 + ck*16);
        bq = *(const v8h*)(wrow + (size_t)r0*16);
        bk = *(const v8h*)(wrow + (size_t)(r0 + 784)*16);
        bv = *(const v8h*)(wrow + (size_t)(r0 + 1568)*16);
      }
      const float cq0 = gcq[r0], ck0 = gcq[r0 + 784], cv0 = gcq[r0 + 1568];
      f32x4 cQ = {cq0, cq0, cq0, cq0};
      f32x4 cK = {ck0, ck0, ck0, ck0};
      f32x4 cV = {cv0, cv0, cv0, cv0};
      f32x4 dq = __builtin_amdgcn_mfma_f32_16x16x32_f16(av, bq, cQ, 0, 0, 0);
      f32x4 dk = __builtin_amdgcn_mfma_f32_16x16x32_f16(av, bk, cK, 0, 0, 0);
      f32x4 dv = __builtin_amdgcn_mfma_f32_16x16x32_f16(av, bv, cV, 0, 0, 0);
      if (ck < 2) {                      // rows b = ck*4+j in 0..7 are valid
        #pragma unroll
        for (int j = 0; j < 4; ++j) {
          const int b = ck*4 + j;
          char* reg = smem + 12544 + (size_t)b * 4096;
          ((_Float16*)reg)[o*56 + sp]          = (_Float16)dq[j];
          ((_Float16*)(reg + 1792))[o*56 + sp] = (_Float16)dk[j];
          ((_Float16*)(gbase + (size_t)b*1568 + sp*32))[o] = (_Float16)dv[j];
        }
      }
    }
  }
  __syncthreads();

  // ---- P3: S1[d,e] via dot2 over s-pairs; lane=(d2,e2) 8x8, loop samples ----
  {
    const u32 d2 = lane >> 3, e2 = lane & 7u;
    #pragma unroll
    for (int u = 0; u < 2; ++u) {
      char* su = pw + u*4096;
      const u32* qw = (const u32*)su;
      const u32* kw = (const u32*)(su + 1792);
      const u32* qA = qw + (2u*d2) * 28u;
      const u32* qB = qA + 28u;
      const u32* kA = kw + (2u*e2) * 28u;
      const u32* kB = kA + 28u;
      float a00 = 0.f, a01 = 0.f, a10 = 0.f, a11 = 0.f;
      #pragma unroll
      for (int t7 = 0; t7 < 6; ++t7) {
        uint4 qa = *(const uint4*)(qA + 4*t7);
        uint4 qb = *(const uint4*)(qB + 4*t7);
        uint4 ka = *(const uint4*)(kA + 4*t7);
        uint4 kb = *(const uint4*)(kB + 4*t7);
        a00 = dot2u(qa.x, ka.x, a00); a00 = dot2u(qa.y, ka.y, a00);
        a00 = dot2u(qa.z, ka.z, a00); a00 = dot2u(qa.w, ka.w, a00);
        a01 = dot2u(qa.x, kb.x, a01); a01 = dot2u(qa.y, kb.y, a01);
        a01 = dot2u(qa.z, kb.z, a01); a01 = dot2u(qa.w, kb.w, a01);
        a10 = dot2u(qb.x, ka.x, a10); a10 = dot2u(qb.y, ka.y, a10);
        a10 = dot2u(qb.z, ka.z, a10); a10 = dot2u(qb.w, ka.w, a10);
        a11 = dot2u(qb.x, kb.x, a11); a11 = dot2u(qb.y, kb.y, a11);
        a11 = dot2u(qb.z, kb.z, a11); a11 = dot2u(qb.w, kb.w, a11);
      }
      {
        float q0t = (float)((const _Float16*)qA)[48];
        float q1t = (float)((const _Float16*)qB)[48];
        float k0t = (float)((const _Float16*)kA)[48];
        float k1t = (float)((const _Float16*)kB)[48];
        a00 = fmaf(q0t, k0t, a00); a01 = fmaf(q0t, k1t, a01);
        a10 = fmaf(q1t, k0t, a10); a11 = fmaf(q1t, k1t, a11);
      }
      u32* s1 = (u32*)(su + 3584);
      s1[(2u*d2)*8u + e2]   = packh2(a00, a01);
      s1[(2u*d2+1)*8u + e2] = packh2(a10, a11);
    }
  }
  wfence();

  // ---- P4a: out1 + softmax16 -> th4 (V1 read from g) ----
  if (s < 49u) {
    #pragma unroll
    for (int u = 0; u < 2; ++u) {
      char* su = pw + u*4096;
      const u32* s1 = (const u32*)(su + 3584);
      const uint4* vv = (const uint4*)(gbase + (size_t)(wv*2u + u)*1568 + s*32u);
      uint4 v0 = vv[0], v1 = vv[1];
      float od[16];
      #pragma unroll
      for (int d = 0; d < 16; ++d) {
        uint4 sa = *(const uint4*)&s1[d*8];
        uint4 sb = *(const uint4*)&s1[d*8 + 4];
        float acc = dot2u(sa.x, v0.x, 0.f);
        acc = dot2u(sa.y, v0.y, acc);
        acc = dot2u(sa.z, v0.z, acc);
        acc = dot2u(sa.w, v0.w, acc);
        acc = dot2u(sb.x, v1.x, acc);
        acc = dot2u(sb.y, v1.y, acc);
        acc = dot2u(sb.z, v1.z, acc);
        acc = dot2u(sb.w, v1.w, acc);
        od[d] = acc;
      }
      float m = od[0];
      #pragma unroll
      for (int d = 1; d < 16; ++d) m = fmaxf(m, od[d]);
      float sum = 0.f;
      #pragma unroll
      for (int d = 0; d < 16; ++d) { od[d] = __expf(od[d] - m); sum += od[d]; }
      float rs = 1.0f / sum;
      #pragma unroll
      for (int j = 0; j < 8; ++j) th4[u][j] = packh2(od[2*j]*rs, od[2*j+1]*rs);
    }
  }

  // ---- P4b: proj2, 3-set rotating pipeline (12 sub-blocks) ----
  if (s < 49u) {
    const int si = (int)s;
    struct WSet2 { uint4 a0, b0, a1, b1; };
    WSet2 A, B, C;
#define P4LOAD(S, J) do { \
    const int rr_ = ((J)/3)*98 + si + (((J)%3)==0 ? 0 : (((J)%3)==1 ? 392 : 784)); \
    S.a0 = g2a[rr_]; S.b0 = g2b[rr_]; S.a1 = g2a[rr_+49]; S.b1 = g2b[rr_+49]; } while (0)
#define P4COMP(S, J) do { \
    const int o_ = 2*((J)/3); \
    if (((J)%3) == 0) { \
      _Float16* q0_ = (_Float16*)pw; \
      _Float16* q1_ = (_Float16*)(pw + 4096); \
      q0_[o_*56 + s]     = (_Float16)dot16(th4[0], S.a0, S.b0, 0.f); \
      q0_[(o_+1)*56 + s] = (_Float16)dot16(th4[0], S.a1, S.b1, 0.f); \
      q1_[o_*56 + s]     = (_Float16)dot16(th4[1], S.a0, S.b0, 0.f); \
      q1_[(o_+1)*56 + s] = (_Float16)dot16(th4[1], S.a1, S.b1, 0.f); \
    } else if (((J)%3) == 1) { \
      _Float16* k0_ = (_Float16*)(pw + 896); \
      _Float16* k1_ = (_Float16*)(pw + 4096 + 896); \
      k0_[o_*56 + s]     = (_Float16)dot16(th4[0], S.a0, S.b0, 0.f); \
      k0_[(o_+1)*56 + s] = (_Float16)dot16(th4[0], S.a1, S.b1, 0.f); \
      k1_[o_*56 + s]     = (_Float16)dot16(th4[1], S.a0, S.b0, 0.f); \
      k1_[(o_+1)*56 + s] = (_Float16)dot16(th4[1], S.a1, S.b1, 0.f); \
    } else { \
      v2h[0][(J)/3] = packh2(dot16(th4[0], S.a0, S.b0, 0.f), dot16(th4[0], S.a1, S.b1, 0.f)); \
      v2h[1][(J)/3] = packh2(dot16(th4[1], S.a0, S.b0, 0.f), dot16(th4[1], S.a1, S.b1, 0.f)); \
    } } while (0)
#define P4STEP(LS, CS, J) do { P4LOAD(LS, (J)+2); \
    __builtin_amdgcn_sched_barrier(0); P4COMP(CS, J); } while (0)
    P4LOAD(A, 0); P4LOAD(B, 1);
    P4STEP(C,A,0); P4STEP(A,B,1); P4STEP(B,C,2);
    P4STEP(C,A,3); P4STEP(A,B,4); P4STEP(B,C,5);
    P4STEP(C,A,6); P4STEP(A,B,7); P4STEP(B,C,8);
    P4STEP(C,A,9);
    __builtin_amdgcn_sched_barrier(0); P4COMP(B, 10);
    __builtin_amdgcn_sched_barrier(0); P4COMP(C, 11);
#undef P4STEP
#undef P4COMP
#undef P4LOAD
  }
  wfence();

  // ---- P5: S2[d,e] 8x8; lane=(u, d, e2): 32 lanes per sample ----
  {
    const u32 uu = lane >> 5, d = (lane >> 2) & 7u, e2 = lane & 3u;
    char* su = pw + uu*4096;
    const u32* qw = (const u32*)su;
    const u32* kw = (const u32*)(su + 896);
    const u32* qA = qw + d * 28u;
    const u32* kA = kw + (2u*e2) * 28u;
    const u32* kB = kA + 28u;
    float a0 = 0.f, a1 = 0.f;
    #pragma unroll
    for (int t7 = 0; t7 < 6; ++t7) {
      uint4 qa = *(const uint4*)(qA + 4*t7);
      uint4 ka = *(const uint4*)(kA + 4*t7);
      uint4 kb = *(const uint4*)(kB + 4*t7);
      a0 = dot2u(qa.x, ka.x, a0); a0 = dot2u(qa.y, ka.y, a0);
      a0 = dot2u(qa.z, ka.z, a0); a0 = dot2u(qa.w, ka.w, a0);
      a1 = dot2u(qa.x, kb.x, a1); a1 = dot2u(qa.y, kb.y, a1);
      a1 = dot2u(qa.z, kb.z, a1); a1 = dot2u(qa.w, kb.w, a1);
    }
    {
      float qt = (float)((const _Float16*)qA)[48];
      float k0t = (float)((const _Float16*)kA)[48];
      float k1t = (float)((const _Float16*)kB)[48];
      a0 = fmaf(qt, k0t, a0); a1 = fmaf(qt, k1t, a1);
    }
    u32* s2 = (u32*)(su + 3584);
    s2[d*4u + e2] = packh2(a0, a1);
  }
  wfence();

  // ---- P6: out2 + softmax8 -> t3h ----
  if (s < 49u) {
    #pragma unroll
    for (int u = 0; u < 2; ++u) {
      char* su = pw + u*4096;
      const u32* s2 = (const u32*)(su + 3584);
      float od[8];
      #pragma unroll
      for (int d = 0; d < 8; ++d) {
        uint4 sr = *(const uint4*)&s2[d*4];
        float acc = dot2u(sr.x, v2h[u][0], 0.f);
        acc = dot2u(sr.y, v2h[u][1], acc);
        acc = dot2u(sr.z, v2h[u][2], acc);
        acc = dot2u(sr.w, v2h[u][3], acc);
        od[d] = acc;
      }
      float m = od[0];
      #pragma unroll
      for (int d = 1; d < 8; ++d) m = fmaxf(m, od[d]);
      float sum = 0.f;
      #pragma unroll
      for (int d = 0; d < 8; ++d) { od[d] = __expf(od[d] - m); sum += od[d]; }
      float rs = 1.0f / sum;
      uint4 tw;
      tw.x = packh2(od[0]*rs, od[1]*rs);
      tw.y = packh2(od[2]*rs, od[3]*rs);
      tw.z = packh2(od[4]*rs, od[5]*rs);
      tw.w = packh2(od[6]*rs, od[7]*rs);
      *(uint4*)((u32*)su + s*4u) = tw;    // t3h overwrites dead Q2 region
    }
  }
  wfence();

  // ---- P7: fc1 halves; lane=(u, h, half) ----
  {
    const u32 uu = lane >> 5, h = (lane >> 1) & 15u, half = lane & 1u;
    char* su = pw + uu*4096;
    const u32* t3 = (const u32*)su;
    float acc = half ? 0.f : f1bg[h];
    #pragma unroll
    for (int jj = 0; jj < 25; ++jj) {
      int j = (int)(half * 25u) + jj;
      if (j < 49) {
        uint4 tj = *(const uint4*)&t3[j*4];
        uint4 wj = f1hg[h*49u + (u32)j];
        acc = dot2u(tj.x, wj.x, acc);
        acc = dot2u(tj.y, wj.y, acc);
        acc = dot2u(tj.z, wj.z, acc);
        acc = dot2u(tj.w, wj.w, acc);
      }
    }
    float* prt = (float*)(su + 3584 + 192);
    prt[h*2u + half] = acc;
  }
  wfence();

  // ---- fc2 (merge + relu + dot); lane=(u, c<10) ----
  {
    const u32 uu = lane >> 5, c = lane & 31u;
    char* su = pw + uu*4096;
    if (c < 10u) {
      const float4* pv4 = (const float4*)(su + 3584 + 192);
      float hb[16];
      #pragma unroll
      for (int g = 0; g < 8; ++g) {
        float4 pv = pv4[g];
        hb[2*g]   = fmaxf(pv.x + pv.y, 0.f);
        hb[2*g+1] = fmaxf(pv.z + pv.w, 0.f);
      }
      const float* wr = f2wg + c*16u;
      float acc = f2bg[c];
      #pragma unroll
      for (int h = 0; h < 16; ++h) acc = fmaf(hb[h], wr[h], acc);
      float* lg = (float*)(su + 3584 + 384);
      lg[c] = acc;
    }
  }
  wfence();

  // ---- softmax10 + store ----
  {
    const u32 uu = lane >> 5, c = lane & 31u;
    char* su = pw + uu*4096;
    if (c < 10u) {
      const float* lg = (const float*)(su + 3584 + 384);
      float mx = lg[0];
      #pragma unroll
      for (int i = 1; i < 10; ++i) mx = fmaxf(mx, lg[i]);
      float sum = 0.f;
      #pragma unroll
      for (int i = 0; i < 10; ++i) sum += __expf(lg[i] - mx);
      out[(size_t)(bbase + uu) * 10u + c] = __expf(lg[c] - mx) / sum;
    }
  }
}

extern "C" void kernel_launch(void* const* d_in, const int* in_sizes, int n_in,
                              void* d_out, int out_size, void* d_ws, size_t ws_size,
                              hipStream_t stream)
{
  const float* x   = (const float*)d_in[0];
  const float* pe  = (const float*)d_in[1];
  const float* wq1 = (const float*)d_in[2];
  const float* wk1 = (const float*)d_in[3];
  const float* wv1 = (const float*)d_in[4];
  const float* wq2 = (const float*)d_in[5];
  const float* wk2 = (const float*)d_in[6];
  const float* wv2 = (const float*)d_in[7];
  const float* f1w = (const float*)d_in[8];
  const float* f1b = (const float*)d_in[9];
  const float* f2w = (const float*)d_in[10];
  const float* f2b = (const float*)d_in[11];
  char* ws = (char*)d_ws;
  float* out = (float*)d_out;

  hipLaunchKernelGGL(vit_prep, dim3(27), dim3(256), 0, stream,
                     pe, wq1, wk1, wv1, wq2, wk2, wv2, f1w, f1b, f2w, f2b, ws);
  hipLaunchKernelGGL(vit_main, dim3(2048), dim3(256), 0, stream, x, ws, out);
}

// Round 12
// 289.930 us; speedup vs baseline: 1.0472x; 1.0472x over previous
//
#include <hip/hip_runtime.h>
#include <cstdint>

typedef unsigned int u32;
typedef unsigned short u16;
typedef _Float16 h2 __attribute__((ext_vector_type(2)));
typedef float f32x4 __attribute__((ext_vector_type(4)));

// ---------------- workspace byte offsets (written by vit_prep) ----------------
#define WS_W1A   0        // [3*16*49][8] f16 : W1 i<8   (Q rows pre-scaled 1/7)
#define WS_W1B   37632    // [3*16*49][8] f16 : W1 i 8..16
#define WS_CQ    75264    // f32[2352]  pos-emb-folded bias (Q part pre-scaled)
#define WS_W2A   84672    // [3*8*49][8] f16 : W2 i<8 (Q rows pre-scaled 1/7)
#define WS_W2B   103488   // [3*8*49][8] f16 : W2 i 8..16
#define WS_F1H   122304   // u32[16*196] fc1 weights as f16 pairs (bias NOT folded)
#define WS_F1B   134848   // f32[16]
#define WS_F2W   134912   // f32[160]
#define WS_F2B   135552   // f32[10]

__device__ __forceinline__ u32 packh2(float a, float b) {
  h2 h; h.x = (_Float16)a; h.y = (_Float16)b;
  return __builtin_bit_cast(u32, h);
}
__device__ __forceinline__ float dot2u(u32 a, u32 b, float c) {
#if __has_builtin(__builtin_amdgcn_fdot2)
  return __builtin_amdgcn_fdot2(__builtin_bit_cast(h2, a), __builtin_bit_cast(h2, b), c, false);
#else
  h2 ha = __builtin_bit_cast(h2, a), hb = __builtin_bit_cast(h2, b);
  return c + (float)ha.x * (float)hb.x + (float)ha.y * (float)hb.y;
#endif
}
__device__ __forceinline__ float dot16(const u32* t, uint4 a, uint4 b, float c) {
  c = dot2u(t[0], a.x, c); c = dot2u(t[1], a.y, c);
  c = dot2u(t[2], a.z, c); c = dot2u(t[3], a.w, c);
  c = dot2u(t[4], b.x, c); c = dot2u(t[5], b.y, c);
  c = dot2u(t[6], b.z, c); c = dot2u(t[7], b.w, c);
  return c;
}

// Nontemporal float4 load for x (streamed once; keeps L2 for weights).
__device__ __forceinline__ f32x4 ldnt(const float* p) {
  return __builtin_nontemporal_load((const f32x4*)p);
}

// Wave-level LDS fence (for the wave-private tail phases).
__device__ __forceinline__ void wfence() {
  __builtin_amdgcn_sched_barrier(0);
  asm volatile("s_waitcnt lgkmcnt(0)" ::: "memory");
  __builtin_amdgcn_sched_barrier(0);
}

// ---------------- prep (weights only, 27 blocks) ----------------
extern "C" __global__ void vit_prep(
    const float* __restrict__ pe,
    const float* __restrict__ wq1, const float* __restrict__ wk1, const float* __restrict__ wv1,
    const float* __restrict__ wq2, const float* __restrict__ wk2, const float* __restrict__ wv2,
    const float* __restrict__ fw1, const float* __restrict__ fb1,
    const float* __restrict__ fw2, const float* __restrict__ fb2,
    char* __restrict__ ws)
{
  const int t = blockIdx.x * 256 + threadIdx.x;
  _Float16* w1aH = (_Float16*)(ws + WS_W1A);
  _Float16* w1bH = (_Float16*)(ws + WS_W1B);
  float*    cq   = (float*)(ws + WS_CQ);
  _Float16* w2aH = (_Float16*)(ws + WS_W2A);
  _Float16* w2bH = (_Float16*)(ws + WS_W2B);
  u32* f1h = (u32*)(ws + WS_F1H);
  float* o1b = (float*)(ws + WS_F1B);
  float* o2w = (float*)(ws + WS_F2W);
  float* o2b = (float*)(ws + WS_F2B);

  if (t < 2352) {                       // W1 rows: t = (p*16+o)*49+s
    int p = t / 784, rem = t % 784;
    int o = rem / 49, s = rem % 49;
    const float* W = (p == 0 ? wq1 : (p == 1 ? wk1 : wv1)) + s*512 + o*32;
    float sc = (p == 0) ? (1.0f/7.0f) : 1.0f;   // fold attn scale into Q
    #pragma unroll
    for (int i = 0; i < 8; ++i) w1aH[t*8 + i] = (_Float16)(W[i] * sc);
    #pragma unroll
    for (int i = 0; i < 8; ++i) w1bH[t*8 + i] = (_Float16)(W[8 + i] * sc);
    float acc = 0.f;
    #pragma unroll
    for (int i = 0; i < 16; ++i) acc += pe[s*16 + i] * W[16 + i];
    cq[t] = acc * sc;
  } else if (t < 3528) {                // W2 rows: u = (p*8+o)*49+s
    int u = t - 2352;
    int p = u / 392, rem = u % 392;
    int o = rem / 49, s = rem % 49;
    const float* W = (p == 0 ? wq2 : (p == 1 ? wk2 : wv2)) + s*128 + o*16;
    float sc = (p == 0) ? (1.0f/7.0f) : 1.0f;
    #pragma unroll
    for (int i = 0; i < 8; ++i) w2aH[u*8 + i] = (_Float16)(W[i] * sc);
    #pragma unroll
    for (int i = 0; i < 8; ++i) w2bH[u*8 + i] = (_Float16)(W[8 + i] * sc);
  } else if (t < 6664) {                // fc1 f16 pairs: u = h*196 + jc
    int u = t - 3528;
    int h = u / 196, jc = u % 196;
    f1h[u] = packh2(fw1[h*392 + 2*jc], fw1[h*392 + 2*jc + 1]);
  } else if (t < 6680) {
    int u = t - 6664; o1b[u] = fb1[u];
  } else if (t < 6840) {
    int u = t - 6680; o2w[u] = fw2[u];
  } else if (t < 6850) {
    int u = t - 6840; o2b[u] = fb2[u];
  }
}

// ---------------- main fused kernel ----------------
// Block = 512 (8 waves, 16 samples), grid 1024. W1+CQ staged in LDS for P2;
// W2 restaged over the dead W1 region for P4b (stage-2 overlaps P3). dot2
// path throughout (R11 showed MFMA regresses here). Tail = R8 verbatim.
// LDS map (150208 B, 1 block/CU):
//   [0, 37632)       W1A rows (16B each)   -> overwritten by W2A after P2
//   [37632, 75264)   W1B rows              -> W2B at [18816,37632) in stage-2
//   [75264, 84672)   CQ f32[2352]
//   [84672, 150208)  8 wave regions x 8192 (2 samples x 4096, R8 layout)
// Theory: residual ~20us/wave stall = L2 weight-load latency under 30% L2
// load (36 dependent sub-blocks x 200-400cy, pipeline covers ~200). LDS
// sources are ~120cy -> stall collapses. Weight L2 traffic drops ~10x.
extern "C" __global__ void __launch_bounds__(512, 1)
vit_main(const float* __restrict__ x, const char* __restrict__ ws, float* __restrict__ out)
{
  __shared__ uint4 smem4[150208 / 16];
  char* smem = (char*)smem4;
  const u32 tid  = threadIdx.x;
  const u32 lane = tid & 63u;
  const u32 wv   = tid >> 6;            // 0..7

  const uint4* f1hg = (const uint4*)(ws + WS_F1H);
  const float* f1bg = (const float*)(ws + WS_F1B);
  const float* f2wg = (const float*)(ws + WS_F2W);
  const float* f2bg = (const float*)(ws + WS_F2B);

  char* pw = smem + 84672 + wv * 8192;
  const u32 s = lane;
  const u32 pr = s / 7u, pc = s - pr * 7u;

  const u32 bbase = blockIdx.x * 16u + wv * 2u;

  u32 p2h[2][8];   // patch h2 pairs
  u32 v1h[2][8];   // V1 e-pairs
  u32 th4[2][8];   // tok2 pairs
  u32 v2h[2][4];   // V2 e-pairs

  // ---- stage-1: W1A + W1B + CQ -> LDS (84672 B = 5292 uint4) ----
  {
    const uint4* src = (const uint4*)ws;
    uint4* dst = (uint4*)smem;
    uint4 tmp[10];
    #pragma unroll
    for (int k = 0; k < 10; ++k) tmp[k] = src[tid + k*512];
    uint4 tl;
    const bool last = (tid < 172u);     // 5292 - 5120
    if (last) tl = src[tid + 5120];
    #pragma unroll
    for (int k = 0; k < 10; ++k) dst[tid + k*512] = tmp[k];
    if (last) dst[tid + 5120] = tl;
  }

  // ---- P1: patchify to registers (nt x reads; overlaps staging) ----
  if (s < 49u) {
    #pragma unroll
    for (int u = 0; u < 2; ++u) {
      const float* xb = x + (size_t)(bbase + u) * 2352u;
      #pragma unroll
      for (int r = 0; r < 4; ++r) {
        const float* rp = xb + (4u*pr + r) * 28u + 4u*pc;
        f32x4 rr = ldnt(rp);
        f32x4 gg = ldnt(rp + 784);
        f32x4 bb = ldnt(rp + 1568);
        float g0 = 0.299f*rr.x + 0.587f*gg.x + 0.114f*bb.x;
        float g1 = 0.299f*rr.y + 0.587f*gg.y + 0.114f*bb.y;
        float g2 = 0.299f*rr.z + 0.587f*gg.z + 0.114f*bb.z;
        float g3 = 0.299f*rr.w + 0.587f*gg.w + 0.114f*bb.w;
        p2h[u][r*2]   = packh2(g0, g1);
        p2h[u][r*2+1] = packh2(g2, g3);
      }
    }
  }
  __syncthreads();                       // stage-1 visible to all

  // ---- P2: proj1 from LDS weights ----
  if (s < 49u) {
    const int si = (int)s;
    const uint4* wa  = (const uint4*)smem;             // W1A rows
    const uint4* wb  = (const uint4*)(smem + 37632);   // W1B rows
    const float* cqs = (const float*)(smem + 75264);   // CQ
    _Float16* q0 = (_Float16*)pw;
    _Float16* q1 = (_Float16*)(pw + 4096);
    _Float16* k0 = (_Float16*)(pw + 1792);
    _Float16* k1 = (_Float16*)(pw + 4096 + 1792);
    #pragma unroll
    for (int o = 0; o < 16; ++o) {
      const int r0 = o*49 + si;
      uint4 qa = wa[r0], qb = wb[r0];
      float qc = cqs[r0];
      q0[o*56 + s] = (_Float16)dot16(p2h[0], qa, qb, qc);
      q1[o*56 + s] = (_Float16)dot16(p2h[1], qa, qb, qc);
      uint4 ka = wa[r0 + 784], kb = wb[r0 + 784];
      float kc = cqs[r0 + 784];
      k0[o*56 + s] = (_Float16)dot16(p2h[0], ka, kb, kc);
      k1[o*56 + s] = (_Float16)dot16(p2h[1], ka, kb, kc);
    }
    #pragma unroll
    for (int op = 0; op < 8; ++op) {
      const int r0 = (2*op)*49 + si + 1568;
      uint4 va0 = wa[r0], vb0 = wb[r0];
      uint4 va1 = wa[r0 + 49], vb1 = wb[r0 + 49];
      float vc0 = cqs[r0], vc1 = cqs[r0 + 49];
      v1h[0][op] = packh2(dot16(p2h[0], va0, vb0, vc0), dot16(p2h[0], va1, vb1, vc1));
      v1h[1][op] = packh2(dot16(p2h[1], va0, vb0, vc0), dot16(p2h[1], va1, vb1, vc1));
    }
  }
  __syncthreads();                       // all waves done reading W1

  // ---- stage-2: W2A + W2B over dead W1 region (37632 B = 2352 uint4) ----
  // Overlaps P3 (P3 touches only wave regions); visibility ensured by the
  // __syncthreads before P4b.
  {
    const uint4* src = (const uint4*)(ws + WS_W2A);
    uint4* dst = (uint4*)smem;
    uint4 tmp[4];
    #pragma unroll
    for (int k = 0; k < 4; ++k) tmp[k] = src[tid + k*512];
    uint4 tl;
    const bool last = (tid < 304u);      // 2352 - 2048
    if (last) tl = src[tid + 2048];
    #pragma unroll
    for (int k = 0; k < 4; ++k) dst[tid + k*512] = tmp[k];
    if (last) dst[tid + 2048] = tl;
  }

  // ---- P3: S1[d,e] via dot2 over s-pairs; lane=(d2,e2) 8x8, loop samples ----
  {
    const u32 d2 = lane >> 3, e2 = lane & 7u;
    #pragma unroll
    for (int u = 0; u < 2; ++u) {
      char* su = pw + u*4096;
      const u32* qw = (const u32*)su;
      const u32* kw = (const u32*)(su + 1792);
      const u32* qA = qw + (2u*d2) * 28u;
      const u32* qB = qA + 28u;
      const u32* kA = kw + (2u*e2) * 28u;
      const u32* kB = kA + 28u;
      float a00 = 0.f, a01 = 0.f, a10 = 0.f, a11 = 0.f;
      #pragma unroll
      for (int t7 = 0; t7 < 6; ++t7) {
        uint4 qa = *(const uint4*)(qA + 4*t7);
        uint4 qb = *(const uint4*)(qB + 4*t7);
        uint4 ka = *(const uint4*)(kA + 4*t7);
        uint4 kb = *(const uint4*)(kB + 4*t7);
        a00 = dot2u(qa.x, ka.x, a00); a00 = dot2u(qa.y, ka.y, a00);
        a00 = dot2u(qa.z, ka.z, a00); a00 = dot2u(qa.w, ka.w, a00);
        a01 = dot2u(qa.x, kb.x, a01); a01 = dot2u(qa.y, kb.y, a01);
        a01 = dot2u(qa.z, kb.z, a01); a01 = dot2u(qa.w, kb.w, a01);
        a10 = dot2u(qb.x, ka.x, a10); a10 = dot2u(qb.y, ka.y, a10);
        a10 = dot2u(qb.z, ka.z, a10); a10 = dot2u(qb.w, ka.w, a10);
        a11 = dot2u(qb.x, kb.x, a11); a11 = dot2u(qb.y, kb.y, a11);
        a11 = dot2u(qb.z, kb.z, a11); a11 = dot2u(qb.w, kb.w, a11);
      }
      {
        float q0t = (float)((const _Float16*)qA)[48];
        float q1t = (float)((const _Float16*)qB)[48];
        float k0t = (float)((const _Float16*)kA)[48];
        float k1t = (float)((const _Float16*)kB)[48];
        a00 = fmaf(q0t, k0t, a00); a01 = fmaf(q0t, k1t, a01);
        a10 = fmaf(q1t, k0t, a10); a11 = fmaf(q1t, k1t, a11);
      }
      u32* s1 = (u32*)(su + 3584);
      s1[(2u*d2)*8u + e2]   = packh2(a00, a01);
      s1[(2u*d2+1)*8u + e2] = packh2(a10, a11);
    }
  }
  wfence();

  // ---- P4a: out1 + softmax16 -> th4 ----
  if (s < 49u) {
    #pragma unroll
    for (int u = 0; u < 2; ++u) {
      char* su = pw + u*4096;
      const u32* s1 = (const u32*)(su + 3584);
      float od[16];
      #pragma unroll
      for (int d = 0; d < 16; ++d) {
        uint4 sa = *(const uint4*)&s1[d*8];
        uint4 sb = *(const uint4*)&s1[d*8 + 4];
        float acc = dot2u(sa.x, v1h[u][0], 0.f);
        acc = dot2u(sa.y, v1h[u][1], acc);
        acc = dot2u(sa.z, v1h[u][2], acc);
        acc = dot2u(sa.w, v1h[u][3], acc);
        acc = dot2u(sb.x, v1h[u][4], acc);
        acc = dot2u(sb.y, v1h[u][5], acc);
        acc = dot2u(sb.z, v1h[u][6], acc);
        acc = dot2u(sb.w, v1h[u][7], acc);
        od[d] = acc;
      }
      float m = od[0];
      #pragma unroll
      for (int d = 1; d < 16; ++d) m = fmaxf(m, od[d]);
      float sum = 0.f;
      #pragma unroll
      for (int d = 0; d < 16; ++d) { od[d] = __expf(od[d] - m); sum += od[d]; }
      float rs = 1.0f / sum;
      #pragma unroll
      for (int j = 0; j < 8; ++j) th4[u][j] = packh2(od[2*j]*rs, od[2*j+1]*rs);
    }
  }
  __syncthreads();                       // stage-2 visible to all

  // ---- P4b: proj2 from LDS weights ----
  if (s < 49u) {
    const int si = (int)s;
    const uint4* wa2 = (const uint4*)smem;             // W2A rows
    const uint4* wb2 = (const uint4*)(smem + 18816);   // W2B rows
    _Float16* q0 = (_Float16*)pw;
    _Float16* q1 = (_Float16*)(pw + 4096);
    _Float16* k0 = (_Float16*)(pw + 896);
    _Float16* k1 = (_Float16*)(pw + 4096 + 896);
    #pragma unroll
    for (int o = 0; o < 8; ++o) {
      const int r0 = o*49 + si;
      uint4 qa = wa2[r0], qb = wb2[r0];
      q0[o*56 + s] = (_Float16)dot16(th4[0], qa, qb, 0.f);
      q1[o*56 + s] = (_Float16)dot16(th4[1], qa, qb, 0.f);
      uint4 ka = wa2[r0 + 392], kb = wb2[r0 + 392];
      k0[o*56 + s] = (_Float16)dot16(th4[0], ka, kb, 0.f);
      k1[o*56 + s] = (_Float16)dot16(th4[1], ka, kb, 0.f);
    }
    #pragma unroll
    for (int op = 0; op < 4; ++op) {
      const int r0 = (2*op)*49 + si + 784;
      uint4 va0 = wa2[r0], vb0 = wb2[r0];
      uint4 va1 = wa2[r0 + 49], vb1 = wb2[r0 + 49];
      v2h[0][op] = packh2(dot16(th4[0], va0, vb0, 0.f), dot16(th4[0], va1, vb1, 0.f));
      v2h[1][op] = packh2(dot16(th4[1], va0, vb0, 0.f), dot16(th4[1], va1, vb1, 0.f));
    }
  }
  wfence();

  // ---- P5: S2[d,e] 8x8; lane=(u, d, e2): 32 lanes per sample ----
  {
    const u32 uu = lane >> 5, d = (lane >> 2) & 7u, e2 = lane & 3u;
    char* su = pw + uu*4096;
    const u32* qw = (const u32*)su;
    const u32* kw = (const u32*)(su + 896);
    const u32* qA = qw + d * 28u;
    const u32* kA = kw + (2u*e2) * 28u;
    const u32* kB = kA + 28u;
    float a0 = 0.f, a1 = 0.f;
    #pragma unroll
    for (int t7 = 0; t7 < 6; ++t7) {
      uint4 qa = *(const uint4*)(qA + 4*t7);
      uint4 ka = *(const uint4*)(kA + 4*t7);
      uint4 kb = *(const uint4*)(kB + 4*t7);
      a0 = dot2u(qa.x, ka.x, a0); a0 = dot2u(qa.y, ka.y, a0);
      a0 = dot2u(qa.z, ka.z, a0); a0 = dot2u(qa.w, ka.w, a0);
      a1 = dot2u(qa.x, kb.x, a1); a1 = dot2u(qa.y, kb.y, a1);
      a1 = dot2u(qa.z, kb.z, a1); a1 = dot2u(qa.w, kb.w, a1);
    }
    {
      float qt = (float)((const _Float16*)qA)[48];
      float k0t = (float)((const _Float16*)kA)[48];
      float k1t = (float)((const _Float16*)kB)[48];
      a0 = fmaf(qt, k0t, a0); a1 = fmaf(qt, k1t, a1);
    }
    u32* s2 = (u32*)(su + 3584);
    s2[d*4u + e2] = packh2(a0, a1);
  }
  wfence();

  // ---- P6: out2 + softmax8 -> t3h ----
  if (s < 49u) {
    #pragma unroll
    for (int u = 0; u < 2; ++u) {
      char* su = pw + u*4096;
      const u32* s2 = (const u32*)(su + 3584);
      float od[8];
      #pragma unroll
      for (int d = 0; d < 8; ++d) {
        uint4 sr = *(const uint4*)&s2[d*4];
        float acc = dot2u(sr.x, v2h[u][0], 0.f);
        acc = dot2u(sr.y, v2h[u][1], acc);
        acc = dot2u(sr.z, v2h[u][2], acc);
        acc = dot2u(sr.w, v2h[u][3], acc);
        od[d] = acc;
      }
      float m = od[0];
      #pragma unroll
      for (int d = 1; d < 8; ++d) m = fmaxf(m, od[d]);
      float sum = 0.f;
      #pragma unroll
      for (int d = 0; d < 8; ++d) { od[d] = __expf(od[d] - m); sum += od[d]; }
      float rs = 1.0f / sum;
      uint4 tw;
      tw.x = packh2(od[0]*rs, od[1]*rs);
      tw.y = packh2(od[2]*rs, od[3]*rs);
      tw.z = packh2(od[4]*rs, od[5]*rs);
      tw.w = packh2(od[6]*rs, od[7]*rs);
      *(uint4*)((u32*)su + s*4u) = tw;    // t3h overwrites dead Q2 region
    }
  }
  wfence();

  // ---- P7: fc1 halves; lane=(u, h, half) ----
  {
    const u32 uu = lane >> 5, h = (lane >> 1) & 15u, half = lane & 1u;
    char* su = pw + uu*4096;
    const u32* t3 = (const u32*)su;
    float acc = half ? 0.f : f1bg[h];
    #pragma unroll
    for (int jj = 0; jj < 25; ++jj) {
      int j = (int)(half * 25u) + jj;
      if (j < 49) {
        uint4 tj = *(const uint4*)&t3[j*4];
        uint4 wj = f1hg[h*49u + (u32)j];
        acc = dot2u(tj.x, wj.x, acc);
        acc = dot2u(tj.y, wj.y, acc);
        acc = dot2u(tj.z, wj.z, acc);
        acc = dot2u(tj.w, wj.w, acc);
      }
    }
    float* prt = (float*)(su + 3584 + 192);
    prt[h*2u + half] = acc;
  }
  wfence();

  // ---- fc2 (merge + relu + dot); lane=(u, c<10) ----
  {
    const u32 uu = lane >> 5, c = lane & 31u;
    char* su = pw + uu*4096;
    if (c < 10u) {
      const float4* pv4 = (const float4*)(su + 3584 + 192);
      float hb[16];
      #pragma unroll
      for (int g = 0; g < 8; ++g) {
        float4 pv = pv4[g];
        hb[2*g]   = fmaxf(pv.x + pv.y, 0.f);
        hb[2*g+1] = fmaxf(pv.z + pv.w, 0.f);
      }
      const float* wr = f2wg + c*16u;
      float acc = f2bg[c];
      #pragma unroll
      for (int h = 0; h < 16; ++h) acc = fmaf(hb[h], wr[h], acc);
      float* lg = (float*)(su + 3584 + 384);
      lg[c] = acc;
    }
  }
  wfence();

  // ---- softmax10 + store ----
  {
    const u32 uu = lane >> 5, c = lane & 31u;
    char* su = pw + uu*4096;
    if (c < 10u) {
      const float* lg = (const float*)(su + 3584 + 384);
      float mx = lg[0];
      #pragma unroll
      for (int i = 1; i < 10; ++i) mx = fmaxf(mx, lg[i]);
      float sum = 0.f;
      #pragma unroll
      for (int i = 0; i < 10; ++i) sum += __expf(lg[i] - mx);
      out[(size_t)(bbase + uu) * 10u + c] = __expf(lg[c] - mx) / sum;
    }
  }
}

extern "C" void kernel_launch(void* const* d_in, const int* in_sizes, int n_in,
                              void* d_out, int out_size, void* d_ws, size_t ws_size,
                              hipStream_t stream)
{
  const float* x   = (const float*)d_in[0];
  const float* pe  = (const float*)d_in[1];
  const float* wq1 = (const float*)d_in[2];
  const float* wk1 = (const float*)d_in[3];
  const float* wv1 = (const float*)d_in[4];
  const float* wq2 = (const float*)d_in[5];
  const float* wk2 = (const float*)d_in[6];
  const float* wv2 = (const float*)d_in[7];
  const float* f1w = (const float*)d_in[8];
  const float* f1b = (const float*)d_in[9];
  const float* f2w = (const float*)d_in[10];
  const float* f2b = (const float*)d_in[11];
  char* ws = (char*)d_ws;
  float* out = (float*)d_out;

  hipLaunchKernelGGL(vit_prep, dim3(27), dim3(256), 0, stream,
                     pe, wq1, wk1, wv1, wq2, wk2, wv2, f1w, f1b, f2w, f2b, ws);
  hipLaunchKernelGGL(vit_main, dim3(1024), dim3(512), 0, stream, x, ws, out);
}